// Round 8
// baseline (94.581 us; speedup 1.0000x reference)
//
#include <hip/hip_runtime.h>
#include <hip/hip_bf16.h>

// Problem: B=4096, F=512, C=64, MC=100, TRI=2080, N_all = 64+2080 = 2144
// Pipeline:
//  cvt:    x, [w_mu;w_sigma] -> bf16; ALSO zero-fills dense Ld (upper-tri zeros).
//  gemm:   c_all = x @ W^T + bias. 128x128 tile, BK=64, LDS-staged via
//          global_load_lds(16B) with XOR-swizzled source; 17x32 grid, bijective
//          XCD remap. epilogue: cols<64 -> Mu f32; cols in [64,2144) -> DENSE
//          bf16 L at Ld[b][i][j] (softplus+1e-6 on diagonal) — tri_ij was
//          already computed here, so the triangular->dense expansion is FREE.
//  sample: out = sigmoid(mu + L @ eps) as O^T = (eps^T)(L^T), 16x16x32 MFMA.
//          4096 blocks (1 b each), 8 waves, LDS = Ost only (25.6 KB), ONE
//          barrier: {eps gather + L-frags from global + mu -> 8 MFMA ->
//          sigmoid -> Ost} bar {contiguous dump}.
//          ROUND-7 LESSON: load-flight pipelining didn't help -> latency was
//          never the limiter; the expand/barrier phase machinery was. This
//          round deletes it (expand moved into gemm's existing epilogue).
//          ROUND-6 LESSON: __launch_bounds__ arg2 ~ min-blocks/CU here; (512,4)
//          -> VGPR cap 64. ROUND-4 LESSON: output only via contiguous Ost dump.

typedef short bf16x8 __attribute__((ext_vector_type(8)));   // 8 bf16 in 4 VGPRs
typedef float f32x4 __attribute__((ext_vector_type(4)));

__device__ __forceinline__ unsigned short f2bf(float f) {
    union { float f; unsigned u; } u; u.f = f;
    unsigned r = u.u + 0x7FFFu + ((u.u >> 16) & 1u);   // RNE
    return (unsigned short)(r >> 16);
}

// tri index -> (i,j)  (gemm epilogue only; once per fragment column)
__device__ __forceinline__ void tri_ij(int t, int& i, int& j) {
    i = (int)((sqrtf((float)(8 * t + 1)) - 1.0f) * 0.5f);
    if ((i + 1) * (i + 2) / 2 <= t) ++i;
    if (i * (i + 1) / 2 > t) --i;
    j = t - ((i * (i + 1)) >> 1);
}

__device__ __forceinline__ void gload16(const void* g, void* l) {
    __builtin_amdgcn_global_load_lds(
        (const __attribute__((address_space(1))) void*)g,
        (__attribute__((address_space(3))) void*)l, 16, 0, 0);
}

// ---------------- kernel 1: f32 -> bf16 convert + Ld zero-fill -------------------
__global__ __launch_bounds__(256) void cvt_kernel(
    const float* __restrict__ x, const float* __restrict__ wmu,
    const float* __restrict__ wsig,
    unsigned short* __restrict__ Xb, unsigned short* __restrict__ Wb,
    uint4* __restrict__ Ldz) {
    const int NX = (4096 * 512) / 4;           // x float4s
    const int NW = (2144 * 512) / 4;           // w float4s
    const int NMU = (64 * 512) / 4;
    const int NZ = (4096 * 64 * 64 * 2) / 16;  // Ld uint4 zero-stores
    int tot = NX + NW + NZ;
    for (int i = blockIdx.x * blockDim.x + threadIdx.x; i < tot;
         i += gridDim.x * blockDim.x) {
        if (i < NX + NW) {
            float4 v; unsigned short* dst;
            if (i < NX) {
                v = ((const float4*)x)[i];
                dst = Xb + (size_t)i * 4;
            } else {
                int j = i - NX;
                if (j < NMU) v = ((const float4*)wmu)[j];
                else         v = ((const float4*)wsig)[j - NMU];
                dst = Wb + (size_t)j * 4;
            }
            ushort4 o;
            o.x = f2bf(v.x); o.y = f2bf(v.y); o.z = f2bf(v.z); o.w = f2bf(v.w);
            *(ushort4*)dst = o;
        } else {
            Ldz[i - NX - NW] = make_uint4(0u, 0u, 0u, 0u);
        }
    }
}

// ---------------- kernel 2: GEMM + dense-L epilogue ------------------------------
// 128x128 tile, BK=64, 4 waves (2x2), LDS A[128][64]+B[128][64] bf16 = 32 KB.
__global__ __launch_bounds__(256) void gemm_kernel(
    const unsigned short* __restrict__ Xb, const unsigned short* __restrict__ Wb,
    const float* __restrict__ bmu, const float* __restrict__ bsig,
    float* __restrict__ Mu, unsigned short* __restrict__ Ld) {
    __shared__ __align__(16) unsigned short smem[16384];   // A: [0,8192) B: [8192,16384)

    int flat = blockIdx.y * 17 + blockIdx.x;           // 0..543
    int virt = (flat & 7) * 68 + (flat >> 3);          // bijective XCD remap
    int vbx = virt % 17, vby = virt / 17;
    int r0 = vby * 128, c0 = vbx * 128;

    int tid = threadIdx.x;
    int w = tid >> 6, lane = tid & 63;
    int wr = w >> 1, wc = w & 1;
    int lr = lane & 15, kg = lane >> 4;

    int sr = tid >> 3;                 // 0..31 (row within 32-row stripe)
    int sc = tid & 7;                  // chunk 0..7
    int scx = sc ^ (sr & 7);           // inverse-swizzled source chunk
    const unsigned short* Ag = Xb + (size_t)(r0 + sr) * 512 + scx * 8;
    const unsigned short* Bg = Wb + (size_t)(c0 + sr) * 512 + scx * 8;
    unsigned short* As = smem + tid * 8;           // byte off = tid*16
    unsigned short* Bs = smem + 8192 + tid * 8;

    f32x4 acc[4][4];
    #pragma unroll
    for (int i = 0; i < 4; ++i)
        #pragma unroll
        for (int j = 0; j < 4; ++j) acc[i][j] = (f32x4){0.f, 0.f, 0.f, 0.f};

    for (int kt = 0; kt < 8; ++kt) {
        int k0 = kt * 64;
        #pragma unroll
        for (int i = 0; i < 4; ++i) {
            gload16(Ag + (size_t)i * 32 * 512 + k0, As + i * 2048);
            gload16(Bg + (size_t)i * 32 * 512 + k0, Bs + i * 2048);
        }
        __syncthreads();               // drains vmcnt -> staged tile visible
        #pragma unroll
        for (int h = 0; h < 2; ++h) {
            bf16x8 a[4], bv[4];
            #pragma unroll
            for (int i = 0; i < 4; ++i) {
                int row = wr * 64 + i * 16 + lr;
                int ch = ((h << 2) | kg) ^ (row & 7);
                a[i] = *(const bf16x8*)(smem + row * 64 + ch * 8);
            }
            #pragma unroll
            for (int j = 0; j < 4; ++j) {
                int row = wc * 64 + j * 16 + lr;
                int ch = ((h << 2) | kg) ^ (row & 7);
                bv[j] = *(const bf16x8*)(smem + 8192 + row * 64 + ch * 8);
            }
            #pragma unroll
            for (int i = 0; i < 4; ++i)
                #pragma unroll
                for (int j = 0; j < 4; ++j)
                    acc[i][j] = __builtin_amdgcn_mfma_f32_16x16x32_bf16(
                        a[i], bv[j], acc[i][j], 0, 0, 0);
        }
        __syncthreads();
    }

    int rbase = r0 + wr * 64 + (kg << 2);
    #pragma unroll
    for (int j = 0; j < 4; ++j) {
        int col = c0 + wc * 64 + j * 16 + lr;
        if (col < 64) {                        // mu head (wave-uniform branch)
            float bias = bmu[col];
            #pragma unroll
            for (int i = 0; i < 4; ++i)
                #pragma unroll
                for (int r = 0; r < 4; ++r)
                    Mu[(size_t)(rbase + i * 16 + r) * 64 + col] = acc[i][j][r] + bias;
        } else if (col < 2144) {               // sigma head -> DENSE Ld[b][ti][tj]
            int t = col - 64;
            float bias = bsig[t];
            int ti, tj; tri_ij(t, ti, tj);
            bool dg = (tj == ti);
            int ofs = ti * 64 + tj;
            #pragma unroll
            for (int i = 0; i < 4; ++i) {
                #pragma unroll
                for (int r = 0; r < 4; ++r) {
                    float v = acc[i][j][r] + bias;
                    if (dg) v = (v > 15.f ? v : __logf(1.f + __expf(v))) + 1e-6f;
                    Ld[((size_t)(rbase + i * 16 + r) << 12) + ofs] = f2bf(v);
                }
            }
        }
    }
}

// ---------------- kernel 3: out = sigmoid(mu + L @ eps) --------------------------
// 4096 blocks (1 b each), 8 waves, LDS = Ost only; ONE barrier per block.
// L-fragments read directly from dense Ld (global); no expand, no staging.
__global__ __launch_bounds__(512, 4) void sample_kernel(
    const float* __restrict__ Mu, const unsigned short* __restrict__ Ld,
    const float* __restrict__ eps, float* __restrict__ out) {
    __shared__ __align__(16) float Ost[6400];             // out[b] tile, 25.6 KB

    int b = blockIdx.x;
    int tid = threadIdx.x;
    int w = tid >> 6, lane = tid & 63;
    int lr = lane & 15, kg = lane >> 4;
    int m = (w << 4) + lr;
    int ml = (m < 100) ? m : 96;   // clamp: garbage rows never reach Ost
    int m0 = (w << 4) + (kg << 2);
    bool cw = (w < 7);
    bool st = cw && (m0 < 100);

    if (cw) {
        // eps^T A-fragments: 16 direct global f32 loads per lane
        const float* er = eps + (size_t)b * 6400;
        float ef[16];
        #pragma unroll
        for (int s = 0; s < 8; ++s) {
            ef[s]     = er[(kg * 8 + s) * 100 + ml];
            ef[s + 8] = er[(32 + kg * 8 + s) * 100 + ml];
        }
        // mu
        float muv[4];
        #pragma unroll
        for (int g = 0; g < 4; ++g)
            muv[g] = Mu[((size_t)b << 6) + g * 16 + lr];
        // pack eps frags
        bf16x8 a0, a1;
        #pragma unroll
        for (int s = 0; s < 4; ++s) {
            __hip_bfloat162 h0 = __float22bfloat162_rn(
                make_float2(ef[2 * s], ef[2 * s + 1]));
            __hip_bfloat162 h1 = __float22bfloat162_rn(
                make_float2(ef[8 + 2 * s], ef[8 + 2 * s + 1]));
            ((unsigned*)&a0)[s] = *(unsigned*)&h0;
            ((unsigned*)&a1)[s] = *(unsigned*)&h1;
        }
        // per-g: L rows straight from global, 2 MFMA, sigmoid -> Ost
        const unsigned short* lb = Ld + ((size_t)b << 12);
        #pragma unroll
        for (int g = 0; g < 4; ++g) {
            int i = g * 16 + lr;
            bf16x8 L0 = *(const bf16x8*)(lb + i * 64 + kg * 8);
            bf16x8 L1 = *(const bf16x8*)(lb + i * 64 + (kg + 4) * 8);
            f32x4 acc = {0.f, 0.f, 0.f, 0.f};
            acc = __builtin_amdgcn_mfma_f32_16x16x32_bf16(a0, L0, acc, 0, 0, 0);
            acc = __builtin_amdgcn_mfma_f32_16x16x32_bf16(a1, L1, acc, 0, 0, 0);
            if (st) {
                float4 o;
                #pragma unroll
                for (int r = 0; r < 4; ++r) {
                    float z = muv[g] + acc[r];
                    ((float*)&o)[r] = __fdividef(1.f, 1.f + __expf(-z));
                }
                *(float4*)&Ost[i * 100 + m0] = o;   // 16B-aligned, 2-way banks
            }
        }
    }

    __syncthreads();                           // Ost complete

    // contiguous 25.6 KB block store (full lines, exact write volume)
    size_t ob = (size_t)b * 6400;
    #pragma unroll
    for (int kk = 0; kk < 4; ++kk) {
        int f = tid + (kk << 9);               // 0..2047
        if (f < 1600)
            *(float4*)(out + ob + f * 4) = ((const float4*)Ost)[f];
    }
}

extern "C" void kernel_launch(void* const* d_in, const int* in_sizes, int n_in,
                              void* d_out, int out_size, void* d_ws, size_t ws_size,
                              hipStream_t stream) {
    const float* x    = (const float*)d_in[0];
    const float* eps  = (const float*)d_in[1];
    const float* wmu  = (const float*)d_in[2];
    const float* bmu  = (const float*)d_in[3];
    const float* wsig = (const float*)d_in[4];
    const float* bsig = (const float*)d_in[5];
    float* out = (float*)d_out;

    char* ws = (char*)d_ws;
    unsigned short* Xb = (unsigned short*)ws;                      //  4,194,304 B
    unsigned short* Wb = (unsigned short*)(ws + 4194304);          //  2,195,456 B
    float*          Mu = (float*)(ws + 4194304 + 2195456);         //  1,048,576 B
    unsigned short* Ld = (unsigned short*)(ws + 7438336);          // 33,554,432 B (dense L)
    // total workspace: 40,992,768 B

    cvt_kernel<<<2048, 256, 0, stream>>>(x, wmu, wsig, Xb, Wb, (uint4*)Ld);
    // N-tail note: bx=16 stages B rows 2144..2175 (reads past Wb into Mu region,
    // allocated workspace) — outputs there are write-guarded; safe.
    gemm_kernel<<<dim3(17, 32), 256, 0, stream>>>(Xb, Wb, bmu, bsig, Mu, Ld);
    sample_kernel<<<4096, 512, 0, stream>>>(Mu, Ld, eps, out);
}

// Round 9
// 90.056 us; speedup vs baseline: 1.0502x; 1.0502x over previous
//
#include <hip/hip_runtime.h>
#include <hip/hip_bf16.h>

// Problem: B=4096, F=512, C=64, MC=100, TRI=2080, N_all = 64+2080 = 2144
// Pipeline:
//  cvt:    x, [w_mu;w_sigma] -> bf16
//  gemm:   c_all = x @ W^T + bias. 128x128 tile, BK=64, LDS-staged via
//          global_load_lds(16B) with XOR-swizzled source; 17x32 grid, bijective
//          XCD remap. epilogue: cols<64 -> Mu f32; cols in [64,2144) -> Sg bf16
//          TRIANGULAR (softplus+1e-6 on diagonal).  [reverted to r7 form:
//          dense-L epilogue cost +21us in scattered-RMW + zero-fill (r8)]
//  sample: out = sigmoid(mu + L @ eps), WAVE-AUTONOMOUS (zero __syncthreads):
//          4096 blocks x 4 waves; wave w owns i-tile w (rows 16w..16w+16) and
//          loops all 7 m-tiles. L-frags loop-invariant, read ONCE per wave
//          straight from triangular Sg (masked u16 loads, j>i -> 0 in regs).
//          Per m-tile: 16 eps dwords (1 addr reg + imm offsets), pack, 2 MFMA,
//          sigmoid -> wave-PRIVATE LDS chunk; final dump = contiguous 6.4 KB
//          per wave (full lines, exact write volume).
//          ROUND-8 LESSON: four structures all ~61us with nothing saturated ->
//          block-wide barrier convoying was the invariant limiter. Removed.
//          ROUND-6 LESSON: VGPR cap ~ 256/launch_bounds_arg2 -> (256,4) = 64.

typedef short bf16x8 __attribute__((ext_vector_type(8)));   // 8 bf16 in 4 VGPRs
typedef float f32x4 __attribute__((ext_vector_type(4)));

__device__ __forceinline__ unsigned short f2bf(float f) {
    union { float f; unsigned u; } u; u.f = f;
    unsigned r = u.u + 0x7FFFu + ((u.u >> 16) & 1u);   // RNE
    return (unsigned short)(r >> 16);
}

// tri index -> (i,j)  (gemm epilogue only; once per fragment column)
__device__ __forceinline__ void tri_ij(int t, int& i, int& j) {
    i = (int)((sqrtf((float)(8 * t + 1)) - 1.0f) * 0.5f);
    if ((i + 1) * (i + 2) / 2 <= t) ++i;
    if (i * (i + 1) / 2 > t) --i;
    j = t - ((i * (i + 1)) >> 1);
}

__device__ __forceinline__ void gload16(const void* g, void* l) {
    __builtin_amdgcn_global_load_lds(
        (const __attribute__((address_space(1))) void*)g,
        (__attribute__((address_space(3))) void*)l, 16, 0, 0);
}

// ---------------- kernel 1: f32 -> bf16 convert (x and concat(w_mu, w_sigma)) ----
__global__ __launch_bounds__(256) void cvt_kernel(
    const float* __restrict__ x, const float* __restrict__ wmu,
    const float* __restrict__ wsig,
    unsigned short* __restrict__ Xb, unsigned short* __restrict__ Wb) {
    const int NX = (4096 * 512) / 4;
    const int NW = (2144 * 512) / 4;
    const int NMU = (64 * 512) / 4;
    int tot = NX + NW;
    for (int i = blockIdx.x * blockDim.x + threadIdx.x; i < tot;
         i += gridDim.x * blockDim.x) {
        float4 v; unsigned short* dst;
        if (i < NX) {
            v = ((const float4*)x)[i];
            dst = Xb + (size_t)i * 4;
        } else {
            int j = i - NX;
            if (j < NMU) v = ((const float4*)wmu)[j];
            else         v = ((const float4*)wsig)[j - NMU];
            dst = Wb + (size_t)j * 4;
        }
        ushort4 o;
        o.x = f2bf(v.x); o.y = f2bf(v.y); o.z = f2bf(v.z); o.w = f2bf(v.w);
        *(ushort4*)dst = o;
    }
}

// ---------------- kernel 2: GEMM + triangular-Sg epilogue ------------------------
// 128x128 tile, BK=64, 4 waves (2x2), LDS A[128][64]+B[128][64] bf16 = 32 KB.
__global__ __launch_bounds__(256) void gemm_kernel(
    const unsigned short* __restrict__ Xb, const unsigned short* __restrict__ Wb,
    const float* __restrict__ bmu, const float* __restrict__ bsig,
    float* __restrict__ Mu, unsigned short* __restrict__ Sg) {
    __shared__ __align__(16) unsigned short smem[16384];   // A: [0,8192) B: [8192,16384)

    int flat = blockIdx.y * 17 + blockIdx.x;           // 0..543
    int virt = (flat & 7) * 68 + (flat >> 3);          // bijective XCD remap
    int vbx = virt % 17, vby = virt / 17;
    int r0 = vby * 128, c0 = vbx * 128;

    int tid = threadIdx.x;
    int w = tid >> 6, lane = tid & 63;
    int wr = w >> 1, wc = w & 1;
    int lr = lane & 15, kg = lane >> 4;

    int sr = tid >> 3;                 // 0..31 (row within 32-row stripe)
    int sc = tid & 7;                  // chunk 0..7
    int scx = sc ^ (sr & 7);           // inverse-swizzled source chunk
    const unsigned short* Ag = Xb + (size_t)(r0 + sr) * 512 + scx * 8;
    const unsigned short* Bg = Wb + (size_t)(c0 + sr) * 512 + scx * 8;
    unsigned short* As = smem + tid * 8;           // byte off = tid*16
    unsigned short* Bs = smem + 8192 + tid * 8;

    f32x4 acc[4][4];
    #pragma unroll
    for (int i = 0; i < 4; ++i)
        #pragma unroll
        for (int j = 0; j < 4; ++j) acc[i][j] = (f32x4){0.f, 0.f, 0.f, 0.f};

    for (int kt = 0; kt < 8; ++kt) {
        int k0 = kt * 64;
        #pragma unroll
        for (int i = 0; i < 4; ++i) {
            gload16(Ag + (size_t)i * 32 * 512 + k0, As + i * 2048);
            gload16(Bg + (size_t)i * 32 * 512 + k0, Bs + i * 2048);
        }
        __syncthreads();               // drains vmcnt -> staged tile visible
        #pragma unroll
        for (int h = 0; h < 2; ++h) {
            bf16x8 a[4], bv[4];
            #pragma unroll
            for (int i = 0; i < 4; ++i) {
                int row = wr * 64 + i * 16 + lr;
                int ch = ((h << 2) | kg) ^ (row & 7);
                a[i] = *(const bf16x8*)(smem + row * 64 + ch * 8);
            }
            #pragma unroll
            for (int j = 0; j < 4; ++j) {
                int row = wc * 64 + j * 16 + lr;
                int ch = ((h << 2) | kg) ^ (row & 7);
                bv[j] = *(const bf16x8*)(smem + 8192 + row * 64 + ch * 8);
            }
            #pragma unroll
            for (int i = 0; i < 4; ++i)
                #pragma unroll
                for (int j = 0; j < 4; ++j)
                    acc[i][j] = __builtin_amdgcn_mfma_f32_16x16x32_bf16(
                        a[i], bv[j], acc[i][j], 0, 0, 0);
        }
        __syncthreads();
    }

    int rbase = r0 + wr * 64 + (kg << 2);
    #pragma unroll
    for (int j = 0; j < 4; ++j) {
        int col = c0 + wc * 64 + j * 16 + lr;
        if (col < 64) {                        // mu head (wave-uniform branch)
            float bias = bmu[col];
            #pragma unroll
            for (int i = 0; i < 4; ++i)
                #pragma unroll
                for (int r = 0; r < 4; ++r)
                    Mu[(size_t)(rbase + i * 16 + r) * 64 + col] = acc[i][j][r] + bias;
        } else if (col < 2144) {               // sigma head -> triangular Sg
            int t = col - 64;
            float bias = bsig[t];
            int ti, tj; tri_ij(t, ti, tj);
            bool dg = (tj == ti);
            #pragma unroll
            for (int i = 0; i < 4; ++i) {
                #pragma unroll
                for (int r = 0; r < 4; ++r) {
                    float v = acc[i][j][r] + bias;
                    if (dg) v = (v > 15.f ? v : __logf(1.f + __expf(v))) + 1e-6f;
                    Sg[(size_t)(rbase + i * 16 + r) * 2080 + t] = f2bf(v);
                }
            }
        }
    }
}

// ---------------- kernel 3: out = sigmoid(mu + L @ eps) --------------------------
// 4096 blocks x 4 waves; wave w owns output rows [16w,16w+16) of its b and is
// FULLY independent: no __syncthreads anywhere. LDS = 4 wave-private 6.4 KB
// chunks (25.6 KB -> 6 blocks/CU, 24 waves).
__global__ __launch_bounds__(256, 4) void sample_kernel(
    const float* __restrict__ Mu, const unsigned short* __restrict__ Sg,
    const float* __restrict__ eps, float* __restrict__ out) {
    __shared__ __align__(16) float Ost[4][1600];   // [wave][16 rows x 100]

    int flat = blockIdx.x;                      // 0..4095
    int b = (flat & 7) * 512 + (flat >> 3);     // bijective XCD remap

    int tid = threadIdx.x;
    int w = tid >> 6, lane = tid & 63;
    int lr = lane & 15, kg = lane >> 4;
    int i = (w << 4) + lr;                      // this lane's output row (B-col)

    // --- L-fragments (loop-invariant): masked u16 loads from triangular Sg ---
    // row i occupies Sg[b][t0 .. t0+i], t0 = i(i+1)/2; j>i must be zero.
    const unsigned short* sgb = Sg + (size_t)b * 2080;
    int t0 = (i * (i + 1)) >> 1;
    bf16x8 L0, L1;
    #pragma unroll
    for (int s = 0; s < 4; ++s) {
        int ja = kg * 8 + 2 * s;
        int jb = ja + 1;
        unsigned va = (ja <= i) ? (unsigned)sgb[t0 + ja] : 0u;
        unsigned vb = (jb <= i) ? (unsigned)sgb[t0 + jb] : 0u;
        ((unsigned*)&L0)[s] = va | (vb << 16);
        int jc = ja + 32, jd = jb + 32;
        unsigned vc = (jc <= i) ? (unsigned)sgb[t0 + jc] : 0u;
        unsigned vd = (jd <= i) ? (unsigned)sgb[t0 + jd] : 0u;
        ((unsigned*)&L1)[s] = vc | (vd << 16);
    }

    float mu = Mu[((size_t)b << 6) + i];
    const float* er = eps + (size_t)b * 6400;

    // --- loop over all 7 m-tiles (pure dataflow, no barriers) ---
    #pragma unroll
    for (int mt = 0; mt < 7; ++mt) {
        int m = (mt << 4) + lr;
        int ml = (m < 100) ? m : 96;            // clamp; garbage never stored
        float ef[16];
        #pragma unroll
        for (int s = 0; s < 8; ++s) {
            ef[s]     = er[(kg * 8 + s) * 100 + ml];
            ef[s + 8] = er[(32 + kg * 8 + s) * 100 + ml];
        }
        bf16x8 a0, a1;
        #pragma unroll
        for (int s = 0; s < 4; ++s) {
            __hip_bfloat162 h0 = __float22bfloat162_rn(
                make_float2(ef[2 * s], ef[2 * s + 1]));
            __hip_bfloat162 h1 = __float22bfloat162_rn(
                make_float2(ef[8 + 2 * s], ef[8 + 2 * s + 1]));
            ((unsigned*)&a0)[s] = *(unsigned*)&h0;
            ((unsigned*)&a1)[s] = *(unsigned*)&h1;
        }
        f32x4 acc = {0.f, 0.f, 0.f, 0.f};
        acc = __builtin_amdgcn_mfma_f32_16x16x32_bf16(a0, L0, acc, 0, 0, 0);
        acc = __builtin_amdgcn_mfma_f32_16x16x32_bf16(a1, L1, acc, 0, 0, 0);
        int m0 = (mt << 4) + (kg << 2);
        if (m0 < 100) {
            float4 o;
            #pragma unroll
            for (int r = 0; r < 4; ++r) {
                float z = mu + acc[r];
                ((float*)&o)[r] = __fdividef(1.f, 1.f + __expf(-z));
            }
            // lane's 4 m-values of row (i within tile = lr): 16B-aligned
            *(float4*)&Ost[w][lr * 100 + m0] = o;
        }
    }

    // --- dump: wave's 16 rows = contiguous 6.4 KB of out[b] (full lines) ---
    // same-wave LDS dependence; compiler inserts lgkmcnt before the reads.
    float* ob = out + (size_t)b * 6400 + w * 1600;
    const float4* src = (const float4*)&Ost[w][0];
    #pragma unroll
    for (int it = 0; it < 7; ++it) {
        int f = it * 64 + lane;                 // 0..447
        if (f < 400)
            ((float4*)ob)[f] = src[f];
    }
}

extern "C" void kernel_launch(void* const* d_in, const int* in_sizes, int n_in,
                              void* d_out, int out_size, void* d_ws, size_t ws_size,
                              hipStream_t stream) {
    const float* x    = (const float*)d_in[0];
    const float* eps  = (const float*)d_in[1];
    const float* wmu  = (const float*)d_in[2];
    const float* bmu  = (const float*)d_in[3];
    const float* wsig = (const float*)d_in[4];
    const float* bsig = (const float*)d_in[5];
    float* out = (float*)d_out;

    char* ws = (char*)d_ws;
    unsigned short* Xb = (unsigned short*)ws;                      // 4,194,304 B
    unsigned short* Wb = (unsigned short*)(ws + 4194304);          // 2,195,456 B
    float*          Mu = (float*)(ws + 4194304 + 2195456);         // 1,048,576 B
    unsigned short* Sg = (unsigned short*)(ws + 4194304 + 2195456 + 1048576); // 17,039,360 B

    cvt_kernel<<<2048, 256, 0, stream>>>(x, wmu, wsig, Xb, Wb);
    // N-tail note: bx=16 stages B rows 2144..2175 (reads past Wb into Mu region,
    // allocated workspace) — outputs there are write-guarded; safe.
    gemm_kernel<<<dim3(17, 32), 256, 0, stream>>>(Xb, Wb, bmu, bsig, Mu, Sg);
    sample_kernel<<<4096, 256, 0, stream>>>(Mu, Sg, eps, out);
}

// Round 10
// 80.988 us; speedup vs baseline: 1.1678x; 1.1120x over previous
//
#include <hip/hip_runtime.h>
#include <hip/hip_bf16.h>

// Problem: B=4096, F=512, C=64, MC=100, TRI=2080, N_all = 64+2080 = 2144
// Pipeline:
//  cvt:    x, [w_mu;w_sigma] -> bf16
//  gemm:   c_all = x @ W^T + bias. 128x128 tile, BK=64, LDS-staged via
//          global_load_lds(16B) with XOR-swizzled source; 17x32 grid, bijective
//          XCD remap. epilogue: cols<64 -> Mu f32; cols in [64,2144) -> Sg bf16
//          triangular (softplus+1e-6 on diagonal).
//  sample: out = sigmoid(mu + L @ eps) as O^T = (eps^T)(L^T), 16x16x32 MFMA.
//          GEMM-SHAPED: 1024 blocks x NB=4 consecutive b, 8 waves, 2 barriers/b:
//            stage: eps via 400 tasks x 4 float4 (vectorized, r2's verified
//                   transpose->swizzled EpT[112][64] bf16) + Sg via gload16.
//            compute: waves 0-6 own m-tile w; A-frags = 2 ds_read_b128 from
//                   EpT; L-frags = masked ds_read_u16 from Sgs (j>i -> 0);
//                   8 MFMA + sigmoid -> flat Ost.
//            dump: contiguous 1600-float4 store (exact writes); stage(b+1)
//                   overlaps in the same phase.
//          ROUND-9 LESSON: sample is VMEM-instruction-issue bound (4x scalar
//          loads -> 1.7x slower at same HBM bytes). This round divides VMEM
//          instr count by ~4.5 via float4 staging; LDS serves the gathers.
//          ROUND-6 LESSON: VGPR cap ~ 512/(2*arg2) -> (512,3) = ~85 cap.
//          ROUND-4 LESSON: output only via contiguous Ost dump.

typedef short bf16x8 __attribute__((ext_vector_type(8)));   // 8 bf16 in 4 VGPRs
typedef float f32x4 __attribute__((ext_vector_type(4)));

__device__ __forceinline__ unsigned short f2bf(float f) {
    union { float f; unsigned u; } u; u.f = f;
    unsigned r = u.u + 0x7FFFu + ((u.u >> 16) & 1u);   // RNE
    return (unsigned short)(r >> 16);
}

__device__ __forceinline__ int swz(int r) { return (r ^ (r >> 3)) & 7; }

// tri index -> (i,j)  (gemm epilogue only; once per fragment column)
__device__ __forceinline__ void tri_ij(int t, int& i, int& j) {
    i = (int)((sqrtf((float)(8 * t + 1)) - 1.0f) * 0.5f);
    if ((i + 1) * (i + 2) / 2 <= t) ++i;
    if (i * (i + 1) / 2 > t) --i;
    j = t - ((i * (i + 1)) >> 1);
}

__device__ __forceinline__ void gload16(const void* g, void* l) {
    __builtin_amdgcn_global_load_lds(
        (const __attribute__((address_space(1))) void*)g,
        (__attribute__((address_space(3))) void*)l, 16, 0, 0);
}

// ---------------- kernel 1: f32 -> bf16 convert (x and concat(w_mu, w_sigma)) ----
__global__ __launch_bounds__(256) void cvt_kernel(
    const float* __restrict__ x, const float* __restrict__ wmu,
    const float* __restrict__ wsig,
    unsigned short* __restrict__ Xb, unsigned short* __restrict__ Wb) {
    const int NX = (4096 * 512) / 4;
    const int NW = (2144 * 512) / 4;
    const int NMU = (64 * 512) / 4;
    int tot = NX + NW;
    for (int i = blockIdx.x * blockDim.x + threadIdx.x; i < tot;
         i += gridDim.x * blockDim.x) {
        float4 v; unsigned short* dst;
        if (i < NX) {
            v = ((const float4*)x)[i];
            dst = Xb + (size_t)i * 4;
        } else {
            int j = i - NX;
            if (j < NMU) v = ((const float4*)wmu)[j];
            else         v = ((const float4*)wsig)[j - NMU];
            dst = Wb + (size_t)j * 4;
        }
        ushort4 o;
        o.x = f2bf(v.x); o.y = f2bf(v.y); o.z = f2bf(v.z); o.w = f2bf(v.w);
        *(ushort4*)dst = o;
    }
}

// ---------------- kernel 2: GEMM + triangular-Sg epilogue ------------------------
// 128x128 tile, BK=64, 4 waves (2x2), LDS A[128][64]+B[128][64] bf16 = 32 KB.
__global__ __launch_bounds__(256) void gemm_kernel(
    const unsigned short* __restrict__ Xb, const unsigned short* __restrict__ Wb,
    const float* __restrict__ bmu, const float* __restrict__ bsig,
    float* __restrict__ Mu, unsigned short* __restrict__ Sg) {
    __shared__ __align__(16) unsigned short smem[16384];   // A: [0,8192) B: [8192,16384)

    int flat = blockIdx.y * 17 + blockIdx.x;           // 0..543
    int virt = (flat & 7) * 68 + (flat >> 3);          // bijective XCD remap
    int vbx = virt % 17, vby = virt / 17;
    int r0 = vby * 128, c0 = vbx * 128;

    int tid = threadIdx.x;
    int w = tid >> 6, lane = tid & 63;
    int wr = w >> 1, wc = w & 1;
    int lr = lane & 15, kg = lane >> 4;

    int sr = tid >> 3;                 // 0..31 (row within 32-row stripe)
    int sc = tid & 7;                  // chunk 0..7
    int scx = sc ^ (sr & 7);           // inverse-swizzled source chunk
    const unsigned short* Ag = Xb + (size_t)(r0 + sr) * 512 + scx * 8;
    const unsigned short* Bg = Wb + (size_t)(c0 + sr) * 512 + scx * 8;
    unsigned short* As = smem + tid * 8;           // byte off = tid*16
    unsigned short* Bs = smem + 8192 + tid * 8;

    f32x4 acc[4][4];
    #pragma unroll
    for (int i = 0; i < 4; ++i)
        #pragma unroll
        for (int j = 0; j < 4; ++j) acc[i][j] = (f32x4){0.f, 0.f, 0.f, 0.f};

    for (int kt = 0; kt < 8; ++kt) {
        int k0 = kt * 64;
        #pragma unroll
        for (int i = 0; i < 4; ++i) {
            gload16(Ag + (size_t)i * 32 * 512 + k0, As + i * 2048);
            gload16(Bg + (size_t)i * 32 * 512 + k0, Bs + i * 2048);
        }
        __syncthreads();               // drains vmcnt -> staged tile visible
        #pragma unroll
        for (int h = 0; h < 2; ++h) {
            bf16x8 a[4], bv[4];
            #pragma unroll
            for (int i = 0; i < 4; ++i) {
                int row = wr * 64 + i * 16 + lr;
                int ch = ((h << 2) | kg) ^ (row & 7);
                a[i] = *(const bf16x8*)(smem + row * 64 + ch * 8);
            }
            #pragma unroll
            for (int j = 0; j < 4; ++j) {
                int row = wc * 64 + j * 16 + lr;
                int ch = ((h << 2) | kg) ^ (row & 7);
                bv[j] = *(const bf16x8*)(smem + 8192 + row * 64 + ch * 8);
            }
            #pragma unroll
            for (int i = 0; i < 4; ++i)
                #pragma unroll
                for (int j = 0; j < 4; ++j)
                    acc[i][j] = __builtin_amdgcn_mfma_f32_16x16x32_bf16(
                        a[i], bv[j], acc[i][j], 0, 0, 0);
        }
        __syncthreads();
    }

    int rbase = r0 + wr * 64 + (kg << 2);
    #pragma unroll
    for (int j = 0; j < 4; ++j) {
        int col = c0 + wc * 64 + j * 16 + lr;
        if (col < 64) {                        // mu head (wave-uniform branch)
            float bias = bmu[col];
            #pragma unroll
            for (int i = 0; i < 4; ++i)
                #pragma unroll
                for (int r = 0; r < 4; ++r)
                    Mu[(size_t)(rbase + i * 16 + r) * 64 + col] = acc[i][j][r] + bias;
        } else if (col < 2144) {               // sigma head -> triangular Sg
            int t = col - 64;
            float bias = bsig[t];
            int ti, tj; tri_ij(t, ti, tj);
            bool dg = (tj == ti);
            #pragma unroll
            for (int i = 0; i < 4; ++i) {
                #pragma unroll
                for (int r = 0; r < 4; ++r) {
                    float v = acc[i][j][r] + bias;
                    if (dg) v = (v > 15.f ? v : __logf(1.f + __expf(v))) + 1e-6f;
                    Sg[(size_t)(rbase + i * 16 + r) * 2080 + t] = f2bf(v);
                }
            }
        }
    }
}

// ---------------- kernel 3: out = sigmoid(mu + L @ eps) --------------------------
// 1024 blocks x NB=4 consecutive b; 8 waves; 2 barriers/b; LDS 44.1 KB
// (EpT 14.3K + Sgs 4.2K + Ost 25.6K) -> 3 blocks/CU.
__global__ __launch_bounds__(512, 3) void sample_kernel(
    const float* __restrict__ Mu, const unsigned short* __restrict__ Sg,
    const float* __restrict__ eps, float* __restrict__ out) {
    __shared__ __align__(16) unsigned short EpT[112][64];  // eps^T bf16, swizzled
    __shared__ __align__(16) unsigned short Sgs[2080];     // triangular Sg row
    __shared__ __align__(16) float Ost[6400];              // out[b] tile

    int flat = blockIdx.x;                      // 0..1023
    int virt = (flat & 7) * 128 + (flat >> 3);  // bijective XCD remap
    int b0 = virt << 2;

    int tid = threadIdx.x;
    int w = tid >> 6, lane = tid & 63;
    int lr = lane & 15, kg = lane >> 4;
    bool cw = (w < 7);
    int m0 = (w << 4) + (kg << 2);
    bool st = cw && (m0 < 100);
    int mrow = (w << 4) + lr;       // A-frag row; rows >=100 read junk EpT rows
                                    // but MFMA D-row i depends only on A-row i,
                                    // and those rows are never stored.
    int mq = tid % 25, kq = tid / 25;   // eps staging task (tid<400)

    auto stage = [&](int b) {
        if (tid < 260)
            gload16(Sg + (size_t)b * 2080 + tid * 8, &Sgs[tid * 8]);
        if (tid < 400) {
            const float* p = eps + (size_t)b * 6400 + kq * 400 + mq * 4;
            float4 v0 = *(const float4*)(p);
            float4 v1 = *(const float4*)(p + 100);
            float4 v2 = *(const float4*)(p + 200);
            float4 v3 = *(const float4*)(p + 300);
            #pragma unroll
            for (int s = 0; s < 4; ++s) {
                int m = (mq << 2) + s;
                __hip_bfloat162 h0 = __float22bfloat162_rn(
                    make_float2(((const float*)&v0)[s], ((const float*)&v1)[s]));
                __hip_bfloat162 h1 = __float22bfloat162_rn(
                    make_float2(((const float*)&v2)[s], ((const float*)&v3)[s]));
                uint2 u; u.x = *(unsigned*)&h0; u.y = *(unsigned*)&h1;
                int chunk = (kq >> 1) ^ swz(m);
                *(uint2*)&EpT[m][(chunk << 3) | ((kq & 1) << 2)] = u;
            }
        }
    };

    stage(b0);
    __syncthreads();                            // staged(b0) visible

    for (int k = 0; k < 4; ++k) {
        int b = b0 + k;

        // ---- compute(b): waves 0-6, m-tile w ----
        if (cw) {
            int smz = swz(mrow);
            bf16x8 a0 = *(const bf16x8*)&EpT[mrow][(kg ^ smz) << 3];
            bf16x8 a1 = *(const bf16x8*)&EpT[mrow][((kg + 4) ^ smz) << 3];
            float muv[4];
            #pragma unroll
            for (int g = 0; g < 4; ++g)
                muv[g] = Mu[((size_t)b << 6) + g * 16 + lr];
            #pragma unroll
            for (int g = 0; g < 4; ++g) {
                int i = g * 16 + lr;
                int t0 = (i * (i + 1)) >> 1;
                bf16x8 L0, L1;
                #pragma unroll
                for (int s = 0; s < 4; ++s) {
                    int ja = kg * 8 + 2 * s, jb = ja + 1;
                    int jc = ja + 32,        jd = jb + 32;
                    unsigned va = (ja <= i) ? (unsigned)Sgs[t0 + ja] : 0u;
                    unsigned vb = (jb <= i) ? (unsigned)Sgs[t0 + jb] : 0u;
                    ((unsigned*)&L0)[s] = va | (vb << 16);
                    unsigned vc = (jc <= i) ? (unsigned)Sgs[t0 + jc] : 0u;
                    unsigned vd = (jd <= i) ? (unsigned)Sgs[t0 + jd] : 0u;
                    ((unsigned*)&L1)[s] = vc | (vd << 16);
                }
                f32x4 acc = {0.f, 0.f, 0.f, 0.f};
                acc = __builtin_amdgcn_mfma_f32_16x16x32_bf16(a0, L0, acc, 0, 0, 0);
                acc = __builtin_amdgcn_mfma_f32_16x16x32_bf16(a1, L1, acc, 0, 0, 0);
                if (st) {
                    float4 o;
                    #pragma unroll
                    for (int r = 0; r < 4; ++r) {
                        float z = muv[g] + acc[r];
                        ((float*)&o)[r] = __fdividef(1.f, 1.f + __expf(-z));
                    }
                    *(float4*)&Ost[i * 100 + m0] = o;   // 16B-aligned
                }
            }
        }

        __syncthreads();    // Ost ready; EpT/Sgs reads done

        // ---- dump Ost -> out[b] (contiguous, full lines, exact writes) ----
        size_t ob = (size_t)b * 6400;
        #pragma unroll
        for (int kk = 0; kk < 4; ++kk) {
            int f = tid + (kk << 9);            // 0..2047
            if (f < 1600)
                *(float4*)(out + ob + f * 4) = ((const float4*)Ost)[f];
        }

        // ---- stage(b+1): overwrites EpT/Sgs (reads done at barrier above) ----
        if (k < 3) stage(b + 1);

        __syncthreads();    // staged(b+1) visible; Ost dump reads done
    }
}

extern "C" void kernel_launch(void* const* d_in, const int* in_sizes, int n_in,
                              void* d_out, int out_size, void* d_ws, size_t ws_size,
                              hipStream_t stream) {
    const float* x    = (const float*)d_in[0];
    const float* eps  = (const float*)d_in[1];
    const float* wmu  = (const float*)d_in[2];
    const float* bmu  = (const float*)d_in[3];
    const float* wsig = (const float*)d_in[4];
    const float* bsig = (const float*)d_in[5];
    float* out = (float*)d_out;

    char* ws = (char*)d_ws;
    unsigned short* Xb = (unsigned short*)ws;                      // 4,194,304 B
    unsigned short* Wb = (unsigned short*)(ws + 4194304);          // 2,195,456 B
    float*          Mu = (float*)(ws + 4194304 + 2195456);         // 1,048,576 B
    unsigned short* Sg = (unsigned short*)(ws + 4194304 + 2195456 + 1048576); // 17,039,360 B

    cvt_kernel<<<2048, 256, 0, stream>>>(x, wmu, wsig, Xb, Wb);
    // N-tail note: bx=16 stages B rows 2144..2175 (reads past Wb into Mu region,
    // allocated workspace) — outputs there are write-guarded; safe.
    gemm_kernel<<<dim3(17, 32), 256, 0, stream>>>(Xb, Wb, bmu, bsig, Mu, Sg);
    sample_kernel<<<1024, 512, 0, stream>>>(Mu, Sg, eps, out);
}

// Round 11
// 79.079 us; speedup vs baseline: 1.1960x; 1.0241x over previous
//
#include <hip/hip_runtime.h>
#include <hip/hip_bf16.h>

// Problem: B=4096, F=512, C=64, MC=100, TRI=2080, N_all = 64+2080 = 2144
// Pipeline:
//  cvt:    x, [w_mu;w_sigma] -> bf16
//  gemm:   c_all = x @ W^T + bias. 128x128 tile, BK=64, LDS-staged via
//          global_load_lds(16B) with XOR-swizzled source; 17x32 grid, bijective
//          XCD remap. epilogue: cols<64 -> Mu f32; cols in [64,2144) -> Sg bf16
//          triangular (softplus+1e-6 on diagonal).
//  sample: out = sigmoid(mu + L @ eps) as O^T = (eps^T)(L^T), 16x16x32 MFMA.
//          COMPOSITE OF PROVEN-BEST PIECES (10-round evidence):
//          r3 skeleton (best measured, 60.7us): 4096 blocks x 1 b, 8 waves,
//            eps scalar gather direct to regs (NO staging barrier), dense-Lh
//            expand from global Sg (vectorized LDS writes), 2 barriers.
//          + r8's flat Ost[6400] + 16B-aligned writes (measured 0 bank
//            conflicts, exact 102400KB writes) replacing r3's swizzled Ost:
//            LDS 40 -> 33.8 KB, 4 blocks/CU intact.
//          + (512,4) VGPR cap 64 (r6 law: arg2 acts as min-blocks/CU here).
//          Rejected by measurement: eps LDS staging (r2/r10), pipelining
//          (r5/r7), barrier removal w/ dup loads (r9), dense-L in gemm (r8).

typedef short bf16x8 __attribute__((ext_vector_type(8)));   // 8 bf16 in 4 VGPRs
typedef float f32x4 __attribute__((ext_vector_type(4)));

__device__ __forceinline__ unsigned short f2bf(float f) {
    union { float f; unsigned u; } u; u.f = f;
    unsigned r = u.u + 0x7FFFu + ((u.u >> 16) & 1u);   // RNE
    return (unsigned short)(r >> 16);
}

__device__ __forceinline__ int swz(int r) { return (r ^ (r >> 3)) & 7; }

// tri index -> (i,j)  (gemm epilogue only; once per fragment column)
__device__ __forceinline__ void tri_ij(int t, int& i, int& j) {
    i = (int)((sqrtf((float)(8 * t + 1)) - 1.0f) * 0.5f);
    if ((i + 1) * (i + 2) / 2 <= t) ++i;
    if (i * (i + 1) / 2 > t) --i;
    j = t - ((i * (i + 1)) >> 1);
}

__device__ __forceinline__ void gload16(const void* g, void* l) {
    __builtin_amdgcn_global_load_lds(
        (const __attribute__((address_space(1))) void*)g,
        (__attribute__((address_space(3))) void*)l, 16, 0, 0);
}

// ---------------- kernel 1: f32 -> bf16 convert (x and concat(w_mu, w_sigma)) ----
__global__ __launch_bounds__(256) void cvt_kernel(
    const float* __restrict__ x, const float* __restrict__ wmu,
    const float* __restrict__ wsig,
    unsigned short* __restrict__ Xb, unsigned short* __restrict__ Wb) {
    const int NX = (4096 * 512) / 4;
    const int NW = (2144 * 512) / 4;
    const int NMU = (64 * 512) / 4;
    int tot = NX + NW;
    for (int i = blockIdx.x * blockDim.x + threadIdx.x; i < tot;
         i += gridDim.x * blockDim.x) {
        float4 v; unsigned short* dst;
        if (i < NX) {
            v = ((const float4*)x)[i];
            dst = Xb + (size_t)i * 4;
        } else {
            int j = i - NX;
            if (j < NMU) v = ((const float4*)wmu)[j];
            else         v = ((const float4*)wsig)[j - NMU];
            dst = Wb + (size_t)j * 4;
        }
        ushort4 o;
        o.x = f2bf(v.x); o.y = f2bf(v.y); o.z = f2bf(v.z); o.w = f2bf(v.w);
        *(ushort4*)dst = o;
    }
}

// ---------------- kernel 2: GEMM + triangular-Sg epilogue ------------------------
// 128x128 tile, BK=64, 4 waves (2x2), LDS A[128][64]+B[128][64] bf16 = 32 KB.
__global__ __launch_bounds__(256) void gemm_kernel(
    const unsigned short* __restrict__ Xb, const unsigned short* __restrict__ Wb,
    const float* __restrict__ bmu, const float* __restrict__ bsig,
    float* __restrict__ Mu, unsigned short* __restrict__ Sg) {
    __shared__ __align__(16) unsigned short smem[16384];   // A: [0,8192) B: [8192,16384)

    int flat = blockIdx.y * 17 + blockIdx.x;           // 0..543
    int virt = (flat & 7) * 68 + (flat >> 3);          // bijective XCD remap
    int vbx = virt % 17, vby = virt / 17;
    int r0 = vby * 128, c0 = vbx * 128;

    int tid = threadIdx.x;
    int w = tid >> 6, lane = tid & 63;
    int wr = w >> 1, wc = w & 1;
    int lr = lane & 15, kg = lane >> 4;

    int sr = tid >> 3;                 // 0..31 (row within 32-row stripe)
    int sc = tid & 7;                  // chunk 0..7
    int scx = sc ^ (sr & 7);           // inverse-swizzled source chunk
    const unsigned short* Ag = Xb + (size_t)(r0 + sr) * 512 + scx * 8;
    const unsigned short* Bg = Wb + (size_t)(c0 + sr) * 512 + scx * 8;
    unsigned short* As = smem + tid * 8;           // byte off = tid*16
    unsigned short* Bs = smem + 8192 + tid * 8;

    f32x4 acc[4][4];
    #pragma unroll
    for (int i = 0; i < 4; ++i)
        #pragma unroll
        for (int j = 0; j < 4; ++j) acc[i][j] = (f32x4){0.f, 0.f, 0.f, 0.f};

    for (int kt = 0; kt < 8; ++kt) {
        int k0 = kt * 64;
        #pragma unroll
        for (int i = 0; i < 4; ++i) {
            gload16(Ag + (size_t)i * 32 * 512 + k0, As + i * 2048);
            gload16(Bg + (size_t)i * 32 * 512 + k0, Bs + i * 2048);
        }
        __syncthreads();               // drains vmcnt -> staged tile visible
        #pragma unroll
        for (int h = 0; h < 2; ++h) {
            bf16x8 a[4], bv[4];
            #pragma unroll
            for (int i = 0; i < 4; ++i) {
                int row = wr * 64 + i * 16 + lr;
                int ch = ((h << 2) | kg) ^ (row & 7);
                a[i] = *(const bf16x8*)(smem + row * 64 + ch * 8);
            }
            #pragma unroll
            for (int j = 0; j < 4; ++j) {
                int row = wc * 64 + j * 16 + lr;
                int ch = ((h << 2) | kg) ^ (row & 7);
                bv[j] = *(const bf16x8*)(smem + 8192 + row * 64 + ch * 8);
            }
            #pragma unroll
            for (int i = 0; i < 4; ++i)
                #pragma unroll
                for (int j = 0; j < 4; ++j)
                    acc[i][j] = __builtin_amdgcn_mfma_f32_16x16x32_bf16(
                        a[i], bv[j], acc[i][j], 0, 0, 0);
        }
        __syncthreads();
    }

    int rbase = r0 + wr * 64 + (kg << 2);
    #pragma unroll
    for (int j = 0; j < 4; ++j) {
        int col = c0 + wc * 64 + j * 16 + lr;
        if (col < 64) {                        // mu head (wave-uniform branch)
            float bias = bmu[col];
            #pragma unroll
            for (int i = 0; i < 4; ++i)
                #pragma unroll
                for (int r = 0; r < 4; ++r)
                    Mu[(size_t)(rbase + i * 16 + r) * 64 + col] = acc[i][j][r] + bias;
        } else if (col < 2144) {               // sigma head -> triangular Sg
            int t = col - 64;
            float bias = bsig[t];
            int ti, tj; tri_ij(t, ti, tj);
            bool dg = (tj == ti);
            #pragma unroll
            for (int i = 0; i < 4; ++i) {
                #pragma unroll
                for (int r = 0; r < 4; ++r) {
                    float v = acc[i][j][r] + bias;
                    if (dg) v = (v > 15.f ? v : __logf(1.f + __expf(v))) + 1e-6f;
                    Sg[(size_t)(rbase + i * 16 + r) * 2080 + t] = f2bf(v);
                }
            }
        }
    }
}

// ---------------- kernel 3: out = sigmoid(mu + L @ eps) --------------------------
// 4096 blocks x 1 b; 8 waves, wave w<7 owns m-tile w. r3 skeleton + flat Ost.
// LDS 33.8 KB -> 4 blocks/CU (32 waves). Two barriers total.
__global__ __launch_bounds__(512, 4) void sample_kernel(
    const float* __restrict__ Mu, const unsigned short* __restrict__ Sg,
    const float* __restrict__ eps, float* __restrict__ out) {
    __shared__ __align__(16) unsigned short Lh[64][64];   // dense L, swizzled, 8 KB
    __shared__ __align__(16) float Ost[6400];             // out[b] tile, 25.6 KB

    int b = blockIdx.x;
    int tid = threadIdx.x;
    int w = tid >> 6;                          // wave 0..7
    int lane = tid & 63;
    int lr = lane & 15, kg = lane >> 4;
    const float* er = eps + (size_t)b * 6400;

    // --- eps^T A-fragments: 16 direct global f32 loads per lane (w<7) ---
    // lane needs eps^T[m][j] = er[j*100 + m]; 16-lane groups read 64B segments.
    float ef[16];
    int m = (w << 4) + lr;
    int ml = (m < 100) ? m : 96;   // clamp; garbage rows never reach Ost
    int m0 = (w << 4) + (kg << 2);
    bool cw = (w < 7);
    bool st = cw && (m0 < 100);
    if (cw) {
        #pragma unroll
        for (int s = 0; s < 8; ++s) {
            ef[s]     = er[(kg * 8 + s) * 100 + ml];
            ef[s + 8] = er[(32 + kg * 8 + s) * 100 + ml];
        }
    }

    // --- expand Sg[b] -> dense swizzled Lh (dense enum, zero-fill fused) ---
    const unsigned short* sgu = Sg + (size_t)b * 2080;
    #pragma unroll
    for (int k = 0; k < 4; ++k) {
        int idx = tid + (k << 9);              // 0..2047
        int i = idx >> 5;
        int j0 = (idx & 31) << 1;
        unsigned u = 0u;
        if (j0 <= i) {
            int t = ((i * (i + 1)) >> 1) + j0;
            u = sgu[t];
            if (j0 + 1 <= i) u |= ((unsigned)sgu[t + 1]) << 16;
        }
        *(unsigned*)&Lh[i][(((j0 >> 3) ^ swz(i)) << 3) | (j0 & 7)] = u;
    }

    // --- mu + pack eps frags to bf16 (reg-only, pre-barrier) ---
    float muv[4];
    bf16x8 a0, a1;
    if (cw) {
        #pragma unroll
        for (int g = 0; g < 4; ++g) muv[g] = Mu[((size_t)b << 6) + g * 16 + lr];
        #pragma unroll
        for (int s = 0; s < 4; ++s) {
            __hip_bfloat162 h0 = __float22bfloat162_rn(
                make_float2(ef[2 * s], ef[2 * s + 1]));
            __hip_bfloat162 h1 = __float22bfloat162_rn(
                make_float2(ef[8 + 2 * s], ef[8 + 2 * s + 1]));
            ((unsigned*)&a0)[s] = *(unsigned*)&h0;
            ((unsigned*)&a1)[s] = *(unsigned*)&h1;
        }
    }

    __syncthreads();                           // Lh visible

    // --- per-g: L frags from LDS (ds_read_b128, swizzle-clean), 2 MFMA,
    //     sigmoid -> flat Ost (16B-aligned: 0 conflicts, r8-proven) ---
    if (cw) {
        #pragma unroll
        for (int g = 0; g < 4; ++g) {
            int i = g * 16 + lr;
            int si = swz(i);
            bf16x8 L0 = *(const bf16x8*)&Lh[i][(kg ^ si) << 3];
            bf16x8 L1 = *(const bf16x8*)&Lh[i][((kg + 4) ^ si) << 3];
            f32x4 acc = {0.f, 0.f, 0.f, 0.f};
            acc = __builtin_amdgcn_mfma_f32_16x16x32_bf16(a0, L0, acc, 0, 0, 0);
            acc = __builtin_amdgcn_mfma_f32_16x16x32_bf16(a1, L1, acc, 0, 0, 0);
            if (st) {
                float4 o;
                #pragma unroll
                for (int r = 0; r < 4; ++r) {
                    float z = muv[g] + acc[r];
                    ((float*)&o)[r] = __fdividef(1.f, 1.f + __expf(-z));
                }
                *(float4*)&Ost[i * 100 + m0] = o;   // 16B-aligned (100*4 % 16 == 0)
            }
        }
    }

    __syncthreads();                           // Ost complete

    // --- contiguous 25.6 KB block store (full lines, exact write volume) ---
    size_t ob = (size_t)b * 6400;
    #pragma unroll
    for (int kk = 0; kk < 4; ++kk) {
        int f = tid + (kk << 9);               // 0..2047
        if (f < 1600)
            *(float4*)(out + ob + f * 4) = ((const float4*)Ost)[f];
    }
}

extern "C" void kernel_launch(void* const* d_in, const int* in_sizes, int n_in,
                              void* d_out, int out_size, void* d_ws, size_t ws_size,
                              hipStream_t stream) {
    const float* x    = (const float*)d_in[0];
    const float* eps  = (const float*)d_in[1];
    const float* wmu  = (const float*)d_in[2];
    const float* bmu  = (const float*)d_in[3];
    const float* wsig = (const float*)d_in[4];
    const float* bsig = (const float*)d_in[5];
    float* out = (float*)d_out;

    char* ws = (char*)d_ws;
    unsigned short* Xb = (unsigned short*)ws;                      // 4,194,304 B
    unsigned short* Wb = (unsigned short*)(ws + 4194304);          // 2,195,456 B
    float*          Mu = (float*)(ws + 4194304 + 2195456);         // 1,048,576 B
    unsigned short* Sg = (unsigned short*)(ws + 4194304 + 2195456 + 1048576); // 17,039,360 B

    cvt_kernel<<<2048, 256, 0, stream>>>(x, wmu, wsig, Xb, Wb);
    // N-tail note: bx=16 stages B rows 2144..2175 (reads past Wb into Mu region,
    // allocated workspace) — outputs there are write-guarded; safe.
    gemm_kernel<<<dim3(17, 32), 256, 0, stream>>>(Xb, Wb, bmu, bsig, Mu, Sg);
    sample_kernel<<<4096, 512, 0, stream>>>(Mu, Sg, eps, out);
}